// Round 8
// baseline (148.643 us; speedup 1.0000x reference)
//
#include <hip/hip_runtime.h>
#include <hip/hip_bf16.h>

// Block-local matmul: out block (b,i,j)[64x64] = A(b,i,j)[64x64] @ W(i,j)[64x64]
// B=4, M=K=N=4096, BLOCK_NUM=64. HBM floor ~576 MB (~92 us at copy-rate).
// Round 8: global_load_lds DMA staging for A (depth = whole 16KB tile in
// flight per wave-group, register-free), per-wave-private double-buffered
// A tiles -> zero barriers after W prologue, counted vmcnt waits (never 0),
// fp32 fragments read from swizzled LDS, bf16 convert at MFMA time.

typedef short bf16x8 __attribute__((ext_vector_type(8)));
typedef float f32x4 __attribute__((ext_vector_type(4)));

__device__ __forceinline__ unsigned short f2bf(float f) {
    union { float f; unsigned int u; } v; v.f = f;
    unsigned int u = v.u;
    u += 0x7fffu + ((u >> 16) & 1u);   // round-to-nearest-even
    return (unsigned short)(u >> 16);
}

__device__ __forceinline__ bf16x8 pack8(float4 a, float4 b) {
    bf16x8 r;
    r[0] = (short)f2bf(a.x); r[1] = (short)f2bf(a.y);
    r[2] = (short)f2bf(a.z); r[3] = (short)f2bf(a.w);
    r[4] = (short)f2bf(b.x); r[5] = (short)f2bf(b.y);
    r[6] = (short)f2bf(b.z); r[7] = (short)f2bf(b.w);
    return r;
}

#define BBYTES 67108864ull      // 4096*4096*4 (batch stride, bytes)
#define BELEMS 16777216ull      // 4096*4096   (batch stride, elements)

// Counted vmcnt wait + compile-time fence (rule #18): never drains prefetch.
#define WAITV(N) do { asm volatile("s_waitcnt vmcnt(" #N ")" ::: "memory"); \
                      __builtin_amdgcn_sched_barrier(0); } while (0)

__global__ __launch_bounds__(256, 4) void block_matmul_kernel(
    const float* __restrict__ x, const float* __restrict__ w,
    float* __restrict__ out) {
    // LDS (40 KB):
    //  [0,8K)        Ws[n=64][c=64] bf16, 128B rows, XOR-swz ((n&7)<<4), shared
    //  [8K+p*16K)    A buf p: per-wave 4KB strips, [16 rows][256B], fp32,
    //                source-swizzled u ^= ((row&7)<<4) (rule #21 both-sides)
    __shared__ char smem[40960];

    const int t   = threadIdx.x;
    const int l   = t & 63;
    const int wv  = t >> 6;
    const int lr  = l & 15;          // fragment row / D col
    const int lhi = l >> 4;          // 0..3

    // XCD-bijective swizzle (4096 wgs, 512/XCD): each XCD owns 8 contiguous
    // i-rows (32MB x-slab); W hot set ~8MB/XCD -> L2/L3.
    int orig = blockIdx.x;
    int wg   = (orig & 7) * 512 + (orig >> 3);
    int i = wg >> 6;                 // 0..63 row-block
    int j = wg & 63;                 // 0..63 col-block

    const size_t rowbase = (size_t)i * 64;
    const size_t colbase = (size_t)j * 64;

    // ---------------- W prologue (the only barrier) ----------------
    const float* Wb = w + rowbase * 4096 + colbase;
    const int wn = t & 63;           // col within block
    const int cg = t >> 6;           // 16-row c-group
    float wreg[16];
    #pragma unroll
    for (int it = 0; it < 4; ++it)
        #pragma unroll
        for (int r = 0; r < 4; ++r)
            wreg[it * 4 + r] = Wb[(size_t)(cg * 16 + it * 4 + r) * 4096 + wn];
    #pragma unroll
    for (int it = 0; it < 4; ++it) {
        int cc = (cg * 16 + it * 4) * 2;     // byte col in Ws row
        unsigned long long pk =
            (unsigned long long)f2bf(wreg[it * 4 + 0])         |
            ((unsigned long long)f2bf(wreg[it * 4 + 1]) << 16) |
            ((unsigned long long)f2bf(wreg[it * 4 + 2]) << 32) |
            ((unsigned long long)f2bf(wreg[it * 4 + 3]) << 48);
        *reinterpret_cast<unsigned long long*>(
            smem + wn * 128 + (cc ^ ((wn & 7) << 4))) = pk;
    }
    __syncthreads();   // Ws read-only hereafter; all later sync is vmcnt.

    // ---------------- A DMA (global_load_lds) ----------------
    // Wave wv owns rows [wv*16,+16). 4 instrs/tile, 1KB each (4 rows x 256B,
    // 8 full lines). Source address carries the inverse XOR swizzle.
    const char* Axbase = (const char*)x +
        ((rowbase + wv * 16) * 4096 + colbase) * 4;
    const int c16 = (l & 15) * 16;

#define DMA(b_, p_) {                                                         \
    _Pragma("unroll") for (int s = 0; s < 4; ++s) {                           \
        int rl   = s * 4 + lhi;                                               \
        int csrc = c16 ^ ((rl & 7) << 4);                                     \
        const char* gp = Axbase + (size_t)(b_) * BBYTES +                     \
                         (size_t)rl * 16384 + csrc;                           \
        char* lp = smem + 8192 + (p_) * 16384 + wv * 4096 + s * 1024;         \
        __builtin_amdgcn_global_load_lds(                                     \
            (const __attribute__((address_space(1))) void*)gp,                \
            (__attribute__((address_space(3))) void*)lp, 16, 0, 0);           \
    } }

    char* Alane = smem + 8192 + wv * 4096 + lr * 256;   // buf0, this lane's row
    const int fsw = (lr & 7) << 4;

    DMA(0, 0);
    DMA(1, 1);

    // ---------------- batch body ----------------
    // vmem issue order: [b0D(4) b1D(4)][B0: b2D(4) st0(16)]
    //                   [B1: b3D(4) st1(16)][B2: st2(16)][B3: st3(16)]
    // waits: B0 newer-than-b0D=4; B1 =4+16=20; B2 =16+4+16=36; B3 =16+16=32.
#define BATCH(b_, p_, NW, NEXT, HASNEXT) {                                    \
    WAITV(NW);                                                                \
    const char* Ab = Alane + (p_) * 16384;                                    \
    float4 f00 = *reinterpret_cast<const float4*>(                            \
        Ab + ((lhi * 32) ^ fsw));                                             \
    float4 f01 = *reinterpret_cast<const float4*>(                            \
        Ab + ((lhi * 32 + 16) ^ fsw));                                        \
    float4 f10 = *reinterpret_cast<const float4*>(                            \
        Ab + ((128 + lhi * 32) ^ fsw));                                       \
    float4 f11 = *reinterpret_cast<const float4*>(                            \
        Ab + ((128 + lhi * 32 + 16) ^ fsw));                                  \
    bf16x8 af0 = pack8(f00, f01);                                             \
    bf16x8 af1 = pack8(f10, f11);                                             \
    __builtin_amdgcn_sched_barrier(0);                                        \
    if (HASNEXT) DMA(NEXT, p_);                                               \
    f32x4 acc[4];                                                             \
    _Pragma("unroll") for (int nt = 0; nt < 4; ++nt)                          \
        acc[nt] = (f32x4){0.f, 0.f, 0.f, 0.f};                                \
    _Pragma("unroll") for (int nt = 0; nt < 4; ++nt) {                        \
        int bn = nt * 16 + lr;                                                \
        bf16x8 w0 = *reinterpret_cast<const bf16x8*>(                         \
            smem + bn * 128 + ((lhi * 16) ^ ((bn & 7) << 4)));                \
        acc[nt] = __builtin_amdgcn_mfma_f32_16x16x32_bf16(                    \
            af0, w0, acc[nt], 0, 0, 0);                                       \
    }                                                                         \
    _Pragma("unroll") for (int nt = 0; nt < 4; ++nt) {                        \
        int bn = nt * 16 + lr;                                                \
        bf16x8 w1 = *reinterpret_cast<const bf16x8*>(                         \
            smem + bn * 128 + ((64 + lhi * 16) ^ ((bn & 7) << 4)));           \
        acc[nt] = __builtin_amdgcn_mfma_f32_16x16x32_bf16(                    \
            af1, w1, acc[nt], 0, 0, 0);                                       \
    }                                                                         \
    float* Ob = out + (size_t)(b_) * BELEMS +                                 \
                (rowbase + wv * 16) * 4096 + colbase;                         \
    _Pragma("unroll") for (int nt = 0; nt < 4; ++nt)                          \
    _Pragma("unroll") for (int r = 0; r < 4; ++r)                             \
        Ob[(size_t)(lhi * 4 + r) * 4096 + nt * 16 + lr] = acc[nt][r];         \
    }

    BATCH(0, 0, 4,  2, 1);
    BATCH(1, 1, 20, 3, 1);
    BATCH(2, 0, 36, 0, 0);
    BATCH(3, 1, 32, 0, 0);
}

extern "C" void kernel_launch(void* const* d_in, const int* in_sizes, int n_in,
                              void* d_out, int out_size, void* d_ws, size_t ws_size,
                              hipStream_t stream) {
    const float* x = (const float*)d_in[0];   // [4, 4096, 4096] fp32
    const float* w = (const float*)d_in[1];   // [4096, 4096] fp32
    float* out = (float*)d_out;               // [4, 4096, 4096] fp32

    dim3 grid(4096);
    dim3 block(256);
    block_matmul_kernel<<<grid, block, 0, stream>>>(x, w, out);
}

// Round 9
// 128.269 us; speedup vs baseline: 1.1588x; 1.1588x over previous
//
#include <hip/hip_runtime.h>
#include <hip/hip_bf16.h>

// Block-local matmul: out block (b,i,j)[64x64] = A(b,i,j)[64x64] @ W(i,j)[64x64]
// B=4, M=K=N=4096, BLOCK_NUM=64.
// Round 9: DRAM-density design. wg = (b,i,q8) owns a 64x256 tile; every
// global stream (A read, W read, out write) runs in 1KB-contiguous chunks.
// A/W staged bf16+swizzled in 64KB LDS, 2 wg/CU so stage/compute phases of
// the two resident wgs hide each other. W transposed via register 4x4
// repack (no strided global reads anywhere).

typedef short bf16x8 __attribute__((ext_vector_type(8)));
typedef float f32x4 __attribute__((ext_vector_type(4)));

__device__ __forceinline__ unsigned short f2bf(float f) {
    union { float f; unsigned int u; } v; v.f = f;
    unsigned int u = v.u;
    u += 0x7fffu + ((u >> 16) & 1u);   // round-to-nearest-even
    return (unsigned short)(u >> 16);
}

__device__ __forceinline__ unsigned long long pack4(float4 v) {
    return  (unsigned long long)f2bf(v.x)        |
           ((unsigned long long)f2bf(v.y) << 16) |
           ((unsigned long long)f2bf(v.z) << 32) |
           ((unsigned long long)f2bf(v.w) << 48);
}

__device__ __forceinline__ unsigned long long pack4s(float a, float b,
                                                     float c, float d) {
    return  (unsigned long long)f2bf(a)        |
           ((unsigned long long)f2bf(b) << 16) |
           ((unsigned long long)f2bf(c) << 32) |
           ((unsigned long long)f2bf(d) << 48);
}

#define BELEMS 16777216ull   // 4096*4096 (batch stride, elements)

// Wave-local LDS ordering point (does NOT drain vmcnt).
#define FENCE() asm volatile("s_waitcnt lgkmcnt(0)" ::: "memory")

__global__ __launch_bounds__(256, 2) void block_matmul_kernel(
    const float* __restrict__ x, const float* __restrict__ w,
    float* __restrict__ out) {
    // LDS (64 KB):
    //  [0,32K)   As[m=64][k=256] bf16, 512B rows, swz byte^=((m&7)<<4)
    //  [32K,64K) Ws[n=256][c=64] bf16, 128B rows, swz byte^=((n&7)<<4)
    //  epilogue: whole 64K reused as Os[m=64][256 f32], 1KB rows, swz
    __shared__ char smem[65536];

    const int t   = threadIdx.x;
    const int l   = t & 63;
    const int wv  = t >> 6;
    const int lr  = l & 15;
    const int lhi = l >> 4;

    // XCD-bijective swizzle: 4096 wgs, 512/XCD. idx = ((b*64+i)*16)+q8, so
    // each XCD gets one b and a contiguous 32-i slab (dense 32MB x window);
    // same-i XCDs across b share W via L3 (W read once per XCD from L2).
    int orig = blockIdx.x;
    int wg   = (orig & 7) * 512 + (orig >> 3);
    int b  = wg >> 10;          // 0..3
    int i  = (wg >> 4) & 63;    // 0..63
    int q8 = wg & 15;           // 0..15 (256-col window = 4 j-blocks)

    const size_t rowbase = (size_t)i * 64;
    const size_t colbase = (size_t)q8 * 256;

    const float* Ab = x + (size_t)b * BELEMS + rowbase * 4096 + colbase;
    const float* Wb = w + rowbase * 4096 + colbase;
    float*       Ob = out + (size_t)b * BELEMS + rowbase * 4096 + colbase;

    // ---- Issue A loads: wave-private rows [wv*16,+16), one float4 inst per
    //      row = 1KB contiguous run.
    float4 areg[16];
    {
        const float* p = Ab + (size_t)(wv * 16) * 4096 + l * 4;
        #pragma unroll
        for (int s = 0; s < 16; ++s)
            areg[s] = *reinterpret_cast<const float4*>(p + (size_t)s * 4096);
    }
    // ---- Issue W loads: wave covers c-rows [wv*16,+16); per row 4 dword
    //      insts (lane-consecutive 256B each) = same 1KB contiguous run.
    float wreg[16][4];
    {
        const float* p = Wb + (size_t)(wv * 16) * 4096 + l;
        #pragma unroll
        for (int s = 0; s < 16; ++s)
            #pragma unroll
            for (int h = 0; h < 4; ++h)
                wreg[s][h] = p[(size_t)s * 4096 + h * 64];
    }

    // ---- A convert + swizzled LDS write (b64, linear within row).
    #pragma unroll
    for (int s = 0; s < 16; ++s) {
        int m = wv * 16 + s;
        *reinterpret_cast<unsigned long long*>(
            smem + m * 512 + ((l * 8) ^ ((m & 7) << 4))) = pack4(areg[s]);
    }
    // ---- W transpose: thread holds a 4c x 4n block (4 row-iters x 4 h);
    //      pack 4 consecutive c per n -> b64 write to Ws[n][c0..c0+3].
    #pragma unroll
    for (int g = 0; g < 4; ++g) {
        int c0 = wv * 16 + g * 4;
        #pragma unroll
        for (int h = 0; h < 4; ++h) {
            int n = l + h * 64;
            unsigned long long pk = pack4s(wreg[g*4+0][h], wreg[g*4+1][h],
                                           wreg[g*4+2][h], wreg[g*4+3][h]);
            *reinterpret_cast<unsigned long long*>(
                smem + 32768 + n * 128 + ((c0 * 2) ^ ((n & 7) << 4))) = pk;
        }
    }

    __syncthreads();   // Ws is cross-wave; As ordering also covered.

    // ---- MFMA: wave wv owns out rows [wv*16,+16) x 256 cols (4 j-blocks).
    f32x4 acc[4][4];
    #pragma unroll
    for (int a = 0; a < 4; ++a)
        #pragma unroll
        for (int z = 0; z < 4; ++z) acc[a][z] = (f32x4){0.f,0.f,0.f,0.f};

    const int m = wv * 16 + lr;
    #pragma unroll
    for (int jloc = 0; jloc < 4; ++jloc) {
        #pragma unroll
        for (int kt = 0; kt < 2; ++kt) {
            bf16x8 af = *reinterpret_cast<const bf16x8*>(
                smem + m * 512 +
                ((jloc * 128 + kt * 64 + lhi * 16) ^ ((m & 7) << 4)));
            #pragma unroll
            for (int nt = 0; nt < 4; ++nt) {
                int n = jloc * 64 + nt * 16 + lr;
                bf16x8 bfr = *reinterpret_cast<const bf16x8*>(
                    smem + 32768 + n * 128 +
                    ((kt * 64 + lhi * 16) ^ ((n & 7) << 4)));
                acc[jloc][nt] = __builtin_amdgcn_mfma_f32_16x16x32_bf16(
                    af, bfr, acc[jloc][nt], 0, 0, 0);
            }
        }
    }

    __syncthreads();   // all waves' frag reads done before bounce overwrite

    // ---- Bounce: Os[m=64][256 f32], 1KB rows, swz ((m&7)<<4).
    #pragma unroll
    for (int jloc = 0; jloc < 4; ++jloc)
        #pragma unroll
        for (int nt = 0; nt < 4; ++nt)
            #pragma unroll
            for (int r = 0; r < 4; ++r) {
                int mr  = wv * 16 + lhi * 4 + r;
                int col = jloc * 64 + nt * 16 + lr;
                *reinterpret_cast<float*>(
                    smem + mr * 1024 + ((col * 4) ^ ((mr & 7) << 4)))
                    = acc[jloc][nt][r];
            }
    FENCE();   // bounce rows are wave-private: fence suffices

    // ---- Readback + store: per inst one full row = 1KB contiguous run.
    #pragma unroll
    for (int s = 0; s < 16; ++s) {
        int mr = wv * 16 + s;
        f32x4 v = *reinterpret_cast<const f32x4*>(
            smem + mr * 1024 + ((l * 16) ^ ((mr & 7) << 4)));
        *reinterpret_cast<f32x4*>(Ob + (size_t)mr * 4096 + l * 4) = v;
    }
}

extern "C" void kernel_launch(void* const* d_in, const int* in_sizes, int n_in,
                              void* d_out, int out_size, void* d_ws, size_t ws_size,
                              hipStream_t stream) {
    const float* x = (const float*)d_in[0];   // [4, 4096, 4096] fp32
    const float* w = (const float*)d_in[1];   // [4096, 4096] fp32
    float* out = (float*)d_out;               // [4, 4096, 4096] fp32

    dim3 grid(4096);
    dim3 block(256);
    block_matmul_kernel<<<grid, block, 0, stream>>>(x, w, out);
}

// Round 10
// 117.411 us; speedup vs baseline: 1.2660x; 1.0925x over previous
//
#include <hip/hip_runtime.h>
#include <hip/hip_bf16.h>

// Block-local matmul: out block (b,i,j)[64x64] = A(b,i,j)[64x64] @ W(i,j)[64x64]
// B=4, M=K=N=4096, BLOCK_NUM=64.
// Round 10 = Round 7 (best, 120.4us) + NON-TEMPORAL output stores.
// Theory: out (256MB, write-once never-read) was allocating in L3 and
// evicting x+W between graph replays (measured FETCH 164MB vs 64-80MB
// retention floor). nt stores stop the churn.

typedef short bf16x8 __attribute__((ext_vector_type(8)));
typedef float f32x4 __attribute__((ext_vector_type(4)));

__device__ __forceinline__ unsigned short f2bf(float f) {
    union { float f; unsigned int u; } v; v.f = f;
    unsigned int u = v.u;
    u += 0x7fffu + ((u >> 16) & 1u);   // round-to-nearest-even
    return (unsigned short)(u >> 16);
}

__device__ __forceinline__ unsigned long long pack4(float4 v) {
    return  (unsigned long long)f2bf(v.x)        |
           ((unsigned long long)f2bf(v.y) << 16) |
           ((unsigned long long)f2bf(v.z) << 32) |
           ((unsigned long long)f2bf(v.w) << 48);
}

#define BSTRIDE 16777216ull   // 4096*4096 (batch stride, elements)

// Compiler+wave-local ordering point for LDS write->read reuse.
// lgkmcnt(0) waits LDS ops only; vmcnt (global prefetches) stays untouched.
#define FENCE() asm volatile("s_waitcnt lgkmcnt(0)" ::: "memory")

__global__ __launch_bounds__(256, 3) void block_matmul_kernel(
    const float* __restrict__ x, const float* __restrict__ w,
    float* __restrict__ out) {
    // LDS map (48 KB):
    //   [0,16K)   Ws: [n=128][c=64] bf16, 128B rows, XOR-swz, SHARED (1 barrier)
    //   [16K,32K) A slots: per-wave 4KB, [16 rows][128 c] bf16, 256B rows, swz
    //   [32K,48K) bounce:  per-wave 4KB, [16 rows][64 f32], 256B rows, swz
    __shared__ char smem[49152];

    const int t  = threadIdx.x;
    const int l  = t & 63;
    const int wv = t >> 6;
    const int lr = l & 15;
    const int lk = l >> 4;

    // XCD-bijective swizzle (2048 wgs): each XCD owns a contiguous 8-i slab.
    int orig = blockIdx.x;
    int wg   = (orig & 7) * 256 + (orig >> 3);
    int i = wg >> 5;           // 0..63 row-block
    int q = wg & 31;           // 0..31 col-pair (128 cols)

    const size_t rowbase = (size_t)i * 64;
    const size_t colbase = (size_t)q * 128;

    const float* Wb    = w   + rowbase * 4096 + colbase;
    const float* Abase = x   + (rowbase + wv * 16) * 4096 + colbase;
    float*       Obase = out + (rowbase + wv * 16) * 4096 + colbase;

    char* Aslot = smem + 16384 + wv * 4096;
    char* Bslot = smem + 32768 + wv * 4096;

    // ---- W staging loads first (prologue barrier depends only on these).
    const int wn = t & 127;
    const int c0 = (t >> 7) << 2;        // 0 or 4
    float wreg[32];
    #pragma unroll
    for (int it = 0; it < 8; ++it) {
        int c = it * 8 + c0;
        #pragma unroll
        for (int r = 0; r < 4; ++r)
            wreg[it * 4 + r] = Wb[(size_t)(c + r) * 4096 + wn];
    }

    // ---- A loads: wave-private rows [wv*16, +16). Per instr: lanes cover
    // 2 consecutive rows x 512B contiguous = 8 full 128B lines.
    const int rl0 = l >> 5;              // 0..1
    const int u   = l & 31;              // float4 unit within 512B row
    const float* Alane = Abase + (size_t)rl0 * 4096 + u * 4;

#define LOADA(DST, b_) {                                                      \
    const float* Ap = Alane + (size_t)(b_) * BSTRIDE;                         \
    _Pragma("unroll") for (int s = 0; s < 8; ++s)                             \
        DST[s] = *reinterpret_cast<const float4*>(Ap + (size_t)(s * 2) * 4096); }

    float4 aA[8], aB[8];
    LOADA(aA, 0);
    LOADA(aB, 1);

    // ---- W convert + transposed swizzled write: Ws[n][c].
    #pragma unroll
    for (int it = 0; it < 8; ++it) {
        int c = it * 8 + c0;
        unsigned long long pk =
            (unsigned long long)f2bf(wreg[it * 4 + 0])         |
            ((unsigned long long)f2bf(wreg[it * 4 + 1]) << 16) |
            ((unsigned long long)f2bf(wreg[it * 4 + 2]) << 32) |
            ((unsigned long long)f2bf(wreg[it * 4 + 3]) << 48);
        *reinterpret_cast<unsigned long long*>(
            smem + wn * 128 + ((c * 2) ^ ((wn & 7) << 4))) = pk;
    }

    __syncthreads();   // the ONLY barrier; Ws read-only hereafter.

#define STOREA(SRC) {                                                         \
    _Pragma("unroll") for (int s = 0; s < 8; ++s) {                           \
        int rl = s * 2 + rl0;                                                 \
        *reinterpret_cast<unsigned long long*>(                               \
            Aslot + rl * 256 + ((u * 8) ^ ((rl & 7) << 4))) = pack4(SRC[s]); } }

#define BATCH(b_, CUR) {                                                      \
    STOREA(CUR);                                                              \
    if ((b_) < 2) LOADA(CUR, (b_) + 2);                                       \
    FENCE();   /* A-slot writes ordered+complete before fragment reads */     \
    _Pragma("unroll") for (int jj = 0; jj < 2; ++jj) {                        \
        bf16x8 af0 = *reinterpret_cast<const bf16x8*>(                        \
            Aslot + lr * 256 + ((jj * 128 + lk * 16) ^ ((lr & 7) << 4)));     \
        bf16x8 af1 = *reinterpret_cast<const bf16x8*>(                        \
            Aslot + lr * 256 + ((jj * 128 + 64 + lk * 16) ^ ((lr & 7) << 4)));\
        f32x4 acc[4];                                                         \
        _Pragma("unroll") for (int nt = 0; nt < 4; ++nt)                      \
            acc[nt] = (f32x4){0.f, 0.f, 0.f, 0.f};                            \
        _Pragma("unroll") for (int nt = 0; nt < 4; ++nt) {                    \
            int bn = jj * 64 + nt * 16 + lr;                                  \
            bf16x8 w0 = *reinterpret_cast<const bf16x8*>(                     \
                smem + bn * 128 + ((lk * 16) ^ ((bn & 7) << 4)));             \
            acc[nt] = __builtin_amdgcn_mfma_f32_16x16x32_bf16(                \
                af0, w0, acc[nt], 0, 0, 0);                                   \
        }                                                                     \
        _Pragma("unroll") for (int nt = 0; nt < 4; ++nt) {                    \
            int bn = jj * 64 + nt * 16 + lr;                                  \
            bf16x8 w1 = *reinterpret_cast<const bf16x8*>(                     \
                smem + bn * 128 + ((64 + lk * 16) ^ ((bn & 7) << 4)));        \
            acc[nt] = __builtin_amdgcn_mfma_f32_16x16x32_bf16(                \
                af1, w1, acc[nt], 0, 0, 0);                                   \
        }                                                                     \
        FENCE();   /* prior readback reads done before bounce overwrite */    \
        _Pragma("unroll") for (int nt = 0; nt < 4; ++nt)                      \
        _Pragma("unroll") for (int r = 0; r < 4; ++r) {                       \
            int brow = lk * 4 + r;                                            \
            *reinterpret_cast<float*>(                                        \
                Bslot + brow * 256 +                                          \
                (((nt * 16 + lr) * 4) ^ ((brow & 7) << 4))) = acc[nt][r];     \
        }                                                                     \
        FENCE();   /* bounce writes complete before readback */               \
        float* Ob = Obase + (size_t)(b_) * BSTRIDE + jj * 64;                 \
        _Pragma("unroll") for (int s2 = 0; s2 < 4; ++s2) {                    \
            int row = s2 * 4 + lk;                                            \
            int u2  = l & 15;                                                 \
            f32x4 v = *reinterpret_cast<const f32x4*>(                        \
                Bslot + row * 256 + ((u2 * 16) ^ ((row & 7) << 4)));          \
            __builtin_nontemporal_store(v,                                    \
                reinterpret_cast<f32x4*>(Ob + (size_t)row * 4096 + u2 * 4));  \
        }                                                                     \
    } }

    BATCH(0, aA);
    BATCH(1, aB);
    BATCH(2, aA);
    BATCH(3, aB);
}

extern "C" void kernel_launch(void* const* d_in, const int* in_sizes, int n_in,
                              void* d_out, int out_size, void* d_ws, size_t ws_size,
                              hipStream_t stream) {
    const float* x = (const float*)d_in[0];   // [4, 4096, 4096] fp32
    const float* w = (const float*)d_in[1];   // [4096, 4096] fp32
    float* out = (float*)d_out;               // [4, 4096, 4096] fp32

    dim3 grid(2048);
    dim3 block(256);
    block_matmul_kernel<<<grid, block, 0, stream>>>(x, w, out);
}